// Round 7
// baseline (178.591 us; speedup 1.0000x reference)
//
#include <hip/hip_runtime.h>

#define H 256
#define W 256
#define OWID 250
#define NIMG 256               // B*D
#define BAND 10                // output rows per wave; 25*10 == 250 exactly
#define NBANDS 25
#define NBLK (NBANDS * NIMG)   // 6400 partials
#define WPB 4                  // waves (images) per workgroup

// R6 post-mortem: four structurally different kernels all wall at 56-59 us,
// insensitive to occupancy (18->39%), VGPR (96->44), and cache state (warm
// replay identical). Common factor: 20 ds_bpermute (__shfl_down) per row in
// the serial chain on the CU's single DS unit (~250 wave-rows/CU x 20 x ~28
// cyc ~= 58 us). This version has ZERO cross-lane ops: each lane computes
// vertical sums for all 10 columns its 4 outputs need, from overlapping
// global loads (f4 @4t, f4 @4t+4, f2 @4t+8; neighbors re-hit the same L1
// lines). Horizontal 7-tap = per-lane register adds.

__device__ __forceinline__ void load10(const float* __restrict__ row,
                                       int c0, int c1, int c2, float v[10]) {
    float4 a = *(const float4*)(row + c0);
    float4 b = *(const float4*)(row + c1);
    float2 c = *(const float2*)(row + c2);
    v[0] = a.x; v[1] = a.y; v[2] = a.z; v[3] = a.w;
    v[4] = b.x; v[5] = b.y; v[6] = b.z; v[7] = b.w;
    v[8] = c.x; v[9] = c.y;
}

// Horizontal sliding 7-tap from 10 per-lane vertical sums (12 adds).
#define HSUM(S, WA)                                                \
    WA[0] = (((S[0] + S[1]) + (S[2] + S[3])) + ((S[4] + S[5]) + S[6])); \
    WA[1] = WA[0] - S[0] + S[7];                                   \
    WA[2] = WA[1] - S[1] + S[8];                                   \
    WA[3] = WA[2] - S[2] + S[9];

__global__ __launch_bounds__(256) void ssim_band_kernel(
    const float* __restrict__ X, const float* __restrict__ Y,
    float* __restrict__ partial)
{
    const int lane = threadIdx.x & 63;        // owns output cols 4*lane..4*lane+3
    const int wave = threadIdx.x >> 6;        // 0..3 -> image within group
    const int band = blockIdx.x;              // 0..24
    const int img  = blockIdx.y * WPB + wave; // 0..255
    const int r0 = band * BAND;

    const float* Xb = X + ((size_t)img * H + r0) * W;
    const float* Yb = Y + ((size_t)img * H + r0) * W;

    // Per-lane column offsets, clamped in-bounds. Clamped lanes (62,63)
    // produce garbage vertical sums only for window positions that feed
    // output cols >= 250, which are masked out below.
    const int c0 = 4 * lane;
    const int c1 = (c0 + 4 < 252) ? c0 + 4 : 252;   // f4 needs c <= 252
    const int c2 = (c0 + 8 < 254) ? c0 + 8 : 254;   // f2 needs c <= 254

    // Vertical raw moment sums for 10 columns.
    float sx[10], sy[10], sxx[10], syy[10], sxy[10];

    // ---- init: rows 0..5 ----
    {
        float xv[10], yv[10];
        load10(Xb, c0, c1, c2, xv);
        load10(Yb, c0, c1, c2, yv);
        #pragma unroll
        for (int k = 0; k < 10; ++k) {
            sx[k] = xv[k]; sy[k] = yv[k];
            sxx[k] = xv[k] * xv[k];
            syy[k] = yv[k] * yv[k];
            sxy[k] = xv[k] * yv[k];
        }
        #pragma unroll 2
        for (int i = 1; i < 6; ++i) {
            load10(Xb + i * W, c0, c1, c2, xv);
            load10(Yb + i * W, c0, c1, c2, yv);
            #pragma unroll
            for (int k = 0; k < 10; ++k) {
                sx[k] += xv[k];
                sy[k] += yv[k];
                sxx[k] = fmaf(xv[k], xv[k], sxx[k]);
                syy[k] = fmaf(yv[k], yv[k], syy[k]);
                sxy[k] = fmaf(xv[k], yv[k], sxy[k]);
            }
        }
    }

    // SSIM on RAW 7x7 sums (1/49, 1/2401 normalizations cancel in the ratio).
    const float C1N  = 0.2401f;        // 1e-4 * 2401
    const float C2N  = 2.1609f;        // 9e-4 * 2401
    const float COV  = 49.0f / 48.0f;
    const float COV2 = 2.0f * COV;
    float lsum = 0.0f;

    #define HWIN_SSIM()                                                       \
    {                                                                         \
        float wx[4], wy[4], wxx[4], wyy[4], wxy[4];                           \
        HSUM(sx,  wx)                                                         \
        HSUM(sy,  wy)                                                         \
        HSUM(sxx, wxx)                                                        \
        HSUM(syy, wyy)                                                        \
        HSUM(sxy, wxy)                                                        \
        _Pragma("unroll")                                                     \
        for (int s = 0; s < 4; ++s) {                                         \
            const float SX = wx[s], SY = wy[s];                               \
            const float t1 = SX * SY;                                         \
            const float t2 = SX * SX;                                         \
            const float t3 = SY * SY;                                         \
            const float A1 = 2.0f * t1 + C1N;                                 \
            const float B1 = (t2 + t3) + C1N;                                 \
            const float A2 = COV2 * (49.0f * wxy[s] - t1) + C2N;              \
            const float B2 = COV * (49.0f * (wxx[s] + wyy[s]) - (t2 + t3)) + C2N; \
            const float S = (A1 * A2) * __builtin_amdgcn_rcpf(B1 * B2);       \
            if (c0 + s < OWID) lsum += S;                                     \
        }                                                                     \
    }

    // ---- peel j=0: add row 6 (no leaving row) ----
    {
        float xn[10], yn[10];
        load10(Xb + 6 * W, c0, c1, c2, xn);
        load10(Yb + 6 * W, c0, c1, c2, yn);
        #pragma unroll
        for (int k = 0; k < 10; ++k) {
            sx[k] += xn[k];
            sy[k] += yn[k];
            sxx[k] = fmaf(xn[k], xn[k], sxx[k]);
            syy[k] = fmaf(yn[k], yn[k], syy[k]);
            sxy[k] = fmaf(xn[k], yn[k], sxy[k]);
        }
        HWIN_SSIM()
    }

    // ---- rows j=1..9: slide (add row j+6, subtract row j-1 re-read) ----
    #pragma unroll 3
    for (int j = 1; j < BAND; ++j) {
        float xn[10], yn[10], xo[10], yo[10];
        load10(Xb + (j + 6) * W, c0, c1, c2, xn);
        load10(Yb + (j + 6) * W, c0, c1, c2, yn);
        load10(Xb + (j - 1) * W, c0, c1, c2, xo);
        load10(Yb + (j - 1) * W, c0, c1, c2, yo);
        #pragma unroll
        for (int k = 0; k < 10; ++k) {
            sx[k] += xn[k] - xo[k];
            sy[k] += yn[k] - yo[k];
            sxx[k] += xn[k] * xn[k] - xo[k] * xo[k];
            syy[k] += yn[k] * yn[k] - yo[k] * yo[k];
            sxy[k] += xn[k] * yn[k] - xo[k] * yo[k];
        }
        HWIN_SSIM()
    }

    // Wave reduction -> one partial per wave (the only cross-lane ops left,
    // 6 per 640 outputs — negligible).
    #pragma unroll
    for (int off = 32; off > 0; off >>= 1)
        lsum += __shfl_down(lsum, off, 64);
    if (lane == 0) partial[img * NBANDS + band] = lsum;
}

__global__ __launch_bounds__(1024) void ssim_reduce_kernel(
    const float* __restrict__ partial, float* __restrict__ out)
{
    const int tid = threadIdx.x;
    double acc = 0.0;
    for (int i = tid; i < NBLK; i += 1024)
        acc += (double)partial[i];
    #pragma unroll
    for (int off = 32; off > 0; off >>= 1)
        acc += __shfl_down(acc, off, 64);
    __shared__ double wsumd[16];
    if ((tid & 63) == 0) wsumd[tid >> 6] = acc;
    __syncthreads();
    if (tid == 0) {
        double total = 0.0;
        #pragma unroll
        for (int i = 0; i < 16; ++i) total += wsumd[i];
        float loss = (float)(1.0 - total / 16000000.0);
        out[0] = loss; out[1] = loss; out[2] = loss; out[3] = loss;
    }
}

extern "C" void kernel_launch(void* const* d_in, const int* in_sizes, int n_in,
                              void* d_out, int out_size, void* d_ws, size_t ws_size,
                              hipStream_t stream) {
    const float* X = (const float*)d_in[0];
    const float* Y = (const float*)d_in[1];
    // d_in[2] is the uniform 7x7 filter (1/49 everywhere) — constant-folded.
    float* out = (float*)d_out;
    float* partial = (float*)d_ws;   // 6400 floats = 25.6 KB

    hipLaunchKernelGGL(ssim_band_kernel, dim3(NBANDS, NIMG / WPB), dim3(256), 0,
                       stream, X, Y, partial);
    hipLaunchKernelGGL(ssim_reduce_kernel, dim3(1), dim3(1024), 0, stream,
                       partial, out);
}